// Round 3
// baseline (236.675 us; speedup 1.0000x reference)
//
#include <hip/hip_runtime.h>

#define HW 4096

// ---------------- fold BN into pointwise conv weights (parallel) ----------------
// W0T[k*128+o] = w_pw0[o][k] * s1[k];  b0[o] = sum_k w_pw0[o][k] * t1[k]
// grid (2, 8): x = which conv, y = 16-o block. 256 thr = 16 o x 16 k-lanes (8 k each)
__global__ __launch_bounds__(256) void fold_kernel(
    const float* __restrict__ g1, const float* __restrict__ be1,
    const float* __restrict__ m1, const float* __restrict__ v1,
    const float* __restrict__ w0,
    const float* __restrict__ g2, const float* __restrict__ be2,
    const float* __restrict__ m2, const float* __restrict__ v2,
    const float* __restrict__ w1,
    float* __restrict__ W0T, float* __restrict__ b0,
    float* __restrict__ W1T, float* __restrict__ b1)
{
  __shared__ float sc[128], sh[128], part[16][17];
  const int t = threadIdx.x;
  const int half = blockIdx.x;
  const float* g  = half ? g2 : g1;
  const float* be = half ? be2 : be1;
  const float* mm = half ? m2 : m1;
  const float* vv = half ? v2 : v1;
  if (t < 128) {
    float s = g[t] / sqrtf(vv[t] + 1e-5f);
    sc[t] = s;
    sh[t] = be[t] - mm[t] * s;
  }
  __syncthreads();
  const float* wsrc = half ? w1 : w0;
  float* wd = half ? W1T : W0T;
  float* bd = half ? b1 : b0;
  const int o = (blockIdx.y << 4) + (t >> 4);
  const int kl = t & 15;
  float accb = 0.f;
  #pragma unroll
  for (int j = 0; j < 8; ++j) {
    const int k = (kl << 3) + j;
    const float wv = wsrc[o * 128 + k];
    wd[k * 128 + o] = wv * sc[k];
    accb = fmaf(wv, sh[k], accb);
  }
  part[t >> 4][kl] = accb;
  __syncthreads();
  if (kl == 0) {
    float s = 0.f;
    #pragma unroll
    for (int j = 0; j < 16; ++j) s += part[t >> 4][j];
    bd[o] = s;
  }
}

// ---- out[b][o][hw] = sum_c WT[c][o]*act[b][c][hw] + bias[o]. 128x128 tile, 8x8/thr ----
// grid (32, 8): x = 128-col tile of HW, y = batch.
__global__ __launch_bounds__(256) void gemm_wx(
    const float* __restrict__ act, const float* __restrict__ WT,
    const float* __restrict__ bias, float* __restrict__ out)
{
  __shared__ __align__(16) float As[32][128];   // [k][m=o]
  __shared__ __align__(16) float Bs[32][128];   // [k][n=hw]
  const int t = threadIdx.x;
  const int nBase = blockIdx.x << 7;
  const size_t base = (size_t)blockIdx.y * (128 * HW);
  const int tx = t & 15, ty = t >> 4;
  const int m0 = ty << 3, n0 = tx << 3;
  float acc[8][8] = {};

  for (int kc = 0; kc < 4; ++kc) {
    const int kBase = kc << 5;
    for (int i = t; i < 1024; i += 256) {
      const int kr = i >> 5, mc = (i & 31) << 2;
      *(float4*)&As[kr][mc] = *(const float4*)&WT[(size_t)(kBase + kr) * 128 + mc];
    }
    for (int i = t; i < 1024; i += 256) {
      const int kr = i >> 5, nc = (i & 31) << 2;
      *(float4*)&Bs[kr][nc] =
          *(const float4*)&act[base + (size_t)(kBase + kr) * HW + nBase + nc];
    }
    __syncthreads();
    #pragma unroll 4
    for (int k = 0; k < 32; ++k) {
      float a[8], b[8];
      *(float4*)&a[0] = *(const float4*)&As[k][m0];
      *(float4*)&a[4] = *(const float4*)&As[k][m0 + 4];
      *(float4*)&b[0] = *(const float4*)&Bs[k][n0];
      *(float4*)&b[4] = *(const float4*)&Bs[k][n0 + 4];
      #pragma unroll
      for (int i = 0; i < 8; ++i)
        #pragma unroll
        for (int j = 0; j < 8; ++j)
          acc[i][j] = fmaf(a[i], b[j], acc[i][j]);
    }
    __syncthreads();
  }
  #pragma unroll
  for (int i = 0; i < 8; ++i) {
    const float bs = bias[m0 + i];
    float4 r0, r1;
    r0.x = acc[i][0] + bs; r0.y = acc[i][1] + bs; r0.z = acc[i][2] + bs; r0.w = acc[i][3] + bs;
    r1.x = acc[i][4] + bs; r1.y = acc[i][5] + bs; r1.z = acc[i][6] + bs; r1.w = acc[i][7] + bs;
    float* dst = &out[base + (size_t)(m0 + i) * HW + nBase + n0];
    *(float4*)dst = r0;
    *(float4*)(dst + 4) = r1;
  }
}

// ---- C[r][n] = sum_k A[r][k]*B[k][n] (+ bias[n]); A 32768x128 row-major, N=128 ----
// grid (256): 128-row tiles. 8x8/thread.
__global__ __launch_bounds__(256) void gemm_an(
    const float* __restrict__ A, const float* __restrict__ B,
    const float* __restrict__ bias, float* __restrict__ C)
{
  __shared__ __align__(16) float As[32][128];   // [k][m=row], transposed on store
  __shared__ __align__(16) float Bs[32][128];
  const int t = threadIdx.x;
  const int rBase = blockIdx.x << 7;
  const int tx = t & 15, ty = t >> 4;
  const int m0 = ty << 3, n0 = tx << 3;
  float acc[8][8] = {};

  for (int kc = 0; kc < 4; ++kc) {
    const int kBase = kc << 5;
    for (int i = t; i < 1024; i += 256) {
      const int row = i & 127, kq = (i >> 7) << 2;
      const float4 f = *(const float4*)&A[(size_t)(rBase + row) * 128 + kBase + kq];
      As[kq + 0][row] = f.x;
      As[kq + 1][row] = f.y;
      As[kq + 2][row] = f.z;
      As[kq + 3][row] = f.w;
    }
    for (int i = t; i < 1024; i += 256) {
      const int kr = i >> 5, nc = (i & 31) << 2;
      *(float4*)&Bs[kr][nc] = *(const float4*)&B[(size_t)(kBase + kr) * 128 + nc];
    }
    __syncthreads();
    #pragma unroll 4
    for (int k = 0; k < 32; ++k) {
      float a[8], b[8];
      *(float4*)&a[0] = *(const float4*)&As[k][m0];
      *(float4*)&a[4] = *(const float4*)&As[k][m0 + 4];
      *(float4*)&b[0] = *(const float4*)&Bs[k][n0];
      *(float4*)&b[4] = *(const float4*)&Bs[k][n0 + 4];
      #pragma unroll
      for (int i = 0; i < 8; ++i)
        #pragma unroll
        for (int j = 0; j < 8; ++j)
          acc[i][j] = fmaf(a[i], b[j], acc[i][j]);
    }
    __syncthreads();
  }
  #pragma unroll
  for (int i = 0; i < 8; ++i) {
    float4 r0, r1;
    r0.x = acc[i][0]; r0.y = acc[i][1]; r0.z = acc[i][2]; r0.w = acc[i][3];
    r1.x = acc[i][4]; r1.y = acc[i][5]; r1.z = acc[i][6]; r1.w = acc[i][7];
    if (bias) {
      r0.x += bias[n0 + 0]; r0.y += bias[n0 + 1]; r0.z += bias[n0 + 2]; r0.w += bias[n0 + 3];
      r1.x += bias[n0 + 4]; r1.y += bias[n0 + 5]; r1.z += bias[n0 + 6]; r1.w += bias[n0 + 7];
    }
    float* dst = &C[(size_t)(rBase + m0 + i) * 128 + n0];
    *(float4*)dst = r0;
    *(float4*)(dst + 4) = r1;
  }
}

// ---- om: C[r][n] = sum_k A[r][k]*Bom[k][n] + bom[n]; N=32. grid (256) ----
__global__ __launch_bounds__(256) void gemm_om(
    const float* __restrict__ A, const float* __restrict__ B,
    const float* __restrict__ bias, float* __restrict__ C)
{
  __shared__ __align__(16) float As[32][128];
  __shared__ __align__(16) float Bs[32][32];
  const int t = threadIdx.x;
  const int rBase = blockIdx.x << 7;
  const int tx = t & 7, ty = t >> 3;       // 8 x 32
  const int m0 = ty << 2, n0 = tx << 2;    // 4x4 per thread
  float acc[4][4] = {};

  for (int kc = 0; kc < 4; ++kc) {
    const int kBase = kc << 5;
    for (int i = t; i < 1024; i += 256) {
      const int row = i & 127, kq = (i >> 7) << 2;
      const float4 f = *(const float4*)&A[(size_t)(rBase + row) * 128 + kBase + kq];
      As[kq + 0][row] = f.x;
      As[kq + 1][row] = f.y;
      As[kq + 2][row] = f.z;
      As[kq + 3][row] = f.w;
    }
    {
      const int kr = t >> 3, nc = (t & 7) << 2;
      *(float4*)&Bs[kr][nc] = *(const float4*)&B[(size_t)(kBase + kr) * 32 + nc];
    }
    __syncthreads();
    #pragma unroll 8
    for (int k = 0; k < 32; ++k) {
      float a[4], b[4];
      *(float4*)&a[0] = *(const float4*)&As[k][m0];
      *(float4*)&b[0] = *(const float4*)&Bs[k][n0];
      #pragma unroll
      for (int i = 0; i < 4; ++i)
        #pragma unroll
        for (int j = 0; j < 4; ++j)
          acc[i][j] = fmaf(a[i], b[j], acc[i][j]);
    }
    __syncthreads();
  }
  #pragma unroll
  for (int i = 0; i < 4; ++i) {
    float4 r;
    r.x = acc[i][0] + bias[n0 + 0];
    r.y = acc[i][1] + bias[n0 + 1];
    r.z = acc[i][2] + bias[n0 + 2];
    r.w = acc[i][3] + bias[n0 + 3];
    *(float4*)&C[(size_t)(rBase + m0 + i) * 32 + n0] = r;
  }
}

// ---------------- deformable bilinear sampling ----------------
// consecutive blocks sweep one batch (b = blk>>9) for XCD-L2 locality
__global__ __launch_bounds__(256) void dcn_sample(
    const float* __restrict__ value, const float* __restrict__ om,
    float* __restrict__ out)
{
  __shared__ float oms[8][32];
  const int t = threadIdx.x;
  const int blk = blockIdx.x;
  const int b = blk >> 9;
  const int sBase = (blk & 511) << 3;
  const int s = sBase + (t >> 5);
  const int cg = (t & 31) << 2;
  // stage 8 rows x 32 floats of om
  oms[t >> 5][t & 31] = om[((size_t)b * HW + sBase + (t >> 5)) * 32 + (t & 31)];
  __syncthreads();
  const int h = s >> 6, w = s & 63;
  const float* vb = value + (size_t)b * HW * 128;
  const float* omp = oms[t >> 5];
  const float fw = (float)w, fh = (float)h;
  float4 acc = {0.f, 0.f, 0.f, 0.f};
  #pragma unroll
  for (int k = 0; k < 9; ++k) {
    const float kx = (float)(k % 3 - 1);
    const float ky = (float)(k / 3 - 1);
    const float dx = omp[k * 3 + 0];
    const float dy = omp[k * 3 + 1];
    const float m  = omp[k * 3 + 2];
    const float px = fw + kx + dx;
    const float py = fh + ky + dy;
    const float x0f = floorf(px), y0f = floorf(py);
    const float fx = px - x0f, fy = py - y0f;
    const int ix = (int)x0f, iy = (int)y0f;
    #pragma unroll
    for (int cy = 0; cy < 2; ++cy) {
      const int yi = iy + cy;
      const float wy = cy ? fy : 1.f - fy;
      const float vy = (yi >= 0 && yi < 64) ? 1.f : 0.f;
      const int yc = min(max(yi, 0), 63);
      #pragma unroll
      for (int cx = 0; cx < 2; ++cx) {
        const int xi = ix + cx;
        const float wx = cx ? fx : 1.f - fx;
        const float vx = (xi >= 0 && xi < 64) ? 1.f : 0.f;
        const int xc = min(max(xi, 0), 63);
        const float wgt = wx * wy * vx * vy * m;
        const float4 v = *(const float4*)&vb[(size_t)(yc * 64 + xc) * 128 + cg];
        acc.x = fmaf(wgt, v.x, acc.x);
        acc.y = fmaf(wgt, v.y, acc.y);
        acc.z = fmaf(wgt, v.z, acc.z);
        acc.w = fmaf(wgt, v.w, acc.w);
      }
    }
  }
  *(float4*)&out[((size_t)b * HW + s) * 128 + cg] = acc;
}

extern "C" void kernel_launch(void* const* d_in, const int* in_sizes, int n_in,
                              void* d_out, int out_size, void* d_ws, size_t ws_size,
                              hipStream_t stream)
{
  const float* x    = (const float*)d_in[0];
  const float* g1   = (const float*)d_in[1];
  const float* be1  = (const float*)d_in[2];
  const float* m1   = (const float*)d_in[3];
  const float* v1   = (const float*)d_in[4];
  const float* wpw0 = (const float*)d_in[5];
  const float* wvp  = (const float*)d_in[6];
  const float* bvp  = (const float*)d_in[7];
  const float* womW = (const float*)d_in[8];
  const float* bom  = (const float*)d_in[9];
  const float* wop  = (const float*)d_in[10];
  const float* g2   = (const float*)d_in[11];
  const float* be2  = (const float*)d_in[12];
  const float* m2   = (const float*)d_in[13];
  const float* v2   = (const float*)d_in[14];
  const float* wpw1 = (const float*)d_in[15];

  char* ws = (char*)d_ws;
  // Aliasing: y2 dead after valom/om -> samp reuses it; value dead after sample -> out2.
  float* y2    = (float*)(ws + 0);          // 16 MB  (b,o,hw) flat == (b,s,k)
  float* samp  = (float*)(ws + 0);          // 16 MB  (b,s,cg)   [aliases y2]
  float* value = (float*)(ws + 16777216);   // 16 MB  (b,s,cg)
  float* out2  = (float*)(ws + 16777216);   // 16 MB  (b,s,g) flat == (b,c,hw) [aliases value]
  float* omb   = (float*)(ws + 33554432);   //  4 MB  (b,s,32)
  float* W0T   = (float*)(ws + 37748736);   // 64 KB  [c][o]
  float* W1T   = (float*)(ws + 37814272);   // 64 KB
  float* b0    = (float*)(ws + 37879808);   // 512 B
  float* b1    = (float*)(ws + 37880320);   // 512 B

  fold_kernel<<<dim3(2, 8), 256, 0, stream>>>(g1, be1, m1, v1, wpw0,
                                              g2, be2, m2, v2, wpw1,
                                              W0T, b0, W1T, b1);
  gemm_wx<<<dim3(32, 8), 256, 0, stream>>>(x, W0T, b0, y2);
  gemm_an<<<dim3(256), 256, 0, stream>>>(y2, wvp, bvp, value);
  gemm_om<<<dim3(256), 256, 0, stream>>>(y2, womW, bom, omb);
  dcn_sample<<<dim3(4096), 256, 0, stream>>>(value, omb, samp);
  gemm_an<<<dim3(256), 256, 0, stream>>>(samp, wop, nullptr, out2);
  gemm_wx<<<dim3(32, 8), 256, 0, stream>>>(out2, W1T, b1, (float*)d_out);
}

// Round 4
// 169.812 us; speedup vs baseline: 1.3937x; 1.3937x over previous
//
#include <hip/hip_runtime.h>

#define HW 4096
typedef unsigned short ushort;
typedef __attribute__((ext_vector_type(8))) short short8;
typedef __attribute__((ext_vector_type(4))) float f32x4;

__device__ __forceinline__ ushort bf_rne(float f) {
  unsigned u = __float_as_uint(f);
  unsigned r = (u + 0x7fffu + ((u >> 16) & 1u)) >> 16;
  return (ushort)r;
}
__device__ __forceinline__ void split2(float f, ushort& hi, ushort& lo) {
  ushort h = bf_rne(f);
  float hf = __uint_as_float((unsigned)h << 16);
  hi = h;
  lo = bf_rne(f - hf);
}

// ---------------- prep: fold BN into pw weights, split everything to bf16 hi/lo ----
// roles: 0-7 W0 fold (16 o-rows each), 8-15 W1 fold, 16-23 wvp^T, 24-31 wop^T, 32-33 wom^T
__global__ __launch_bounds__(256) void prep(
    const float* __restrict__ g1, const float* __restrict__ be1,
    const float* __restrict__ m1, const float* __restrict__ v1,
    const float* __restrict__ w0,
    const float* __restrict__ g2, const float* __restrict__ be2,
    const float* __restrict__ m2, const float* __restrict__ v2,
    const float* __restrict__ w1,
    const float* __restrict__ wvp, const float* __restrict__ wom,
    const float* __restrict__ wop,
    ushort* __restrict__ W0h, ushort* __restrict__ W0l, float* __restrict__ b0,
    ushort* __restrict__ W1h, ushort* __restrict__ W1l, float* __restrict__ b1,
    ushort* __restrict__ vph, ushort* __restrict__ vpl,
    ushort* __restrict__ oph, ushort* __restrict__ opl,
    ushort* __restrict__ omh, ushort* __restrict__ oml)
{
  const int t = threadIdx.x;
  const int role = blockIdx.x;
  if (role < 16) {
    __shared__ float sc[128], sh[128], part[16][17];
    const int cv = role >> 3;
    const float* g  = cv ? g2 : g1;
    const float* be = cv ? be2 : be1;
    const float* mm = cv ? m2 : m1;
    const float* vv = cv ? v2 : v1;
    if (t < 128) {
      float s = g[t] / sqrtf(vv[t] + 1e-5f);
      sc[t] = s;
      sh[t] = be[t] - mm[t] * s;
    }
    __syncthreads();
    const float* ws = cv ? w1 : w0;
    ushort* dh = cv ? W1h : W0h;
    ushort* dl = cv ? W1l : W0l;
    float* bb  = cv ? b1 : b0;
    const int o = ((role & 7) << 4) + (t >> 4);
    const int kl = t & 15;
    float accb = 0.f;
    #pragma unroll
    for (int j = 0; j < 8; ++j) {
      const int k = (kl << 3) + j;
      const float wv = ws[o * 128 + k];
      ushort hi, lo;
      split2(wv * sc[k], hi, lo);
      dh[o * 128 + k] = hi;
      dl[o * 128 + k] = lo;
      accb = fmaf(wv, sh[k], accb);
    }
    part[t >> 4][kl] = accb;
    __syncthreads();
    if (kl == 0) {
      float s = 0.f;
      #pragma unroll
      for (int j = 0; j < 16; ++j) s += part[t >> 4][j];
      bb[o] = s;
    }
  } else if (role < 32) {
    const int rr = role & 7;
    const float* srcM = (role < 24) ? wvp : wop;
    ushort* dh = (role < 24) ? vph : oph;
    ushort* dl = (role < 24) ? vpl : opl;
    const int n = (rr << 4) + (t >> 4);
    const int kl = t & 15;
    #pragma unroll
    for (int j = 0; j < 8; ++j) {
      const int k = (kl << 3) + j;
      ushort hi, lo;
      split2(srcM[k * 128 + n], hi, lo);
      dh[n * 128 + k] = hi;
      dl[n * 128 + k] = lo;
    }
  } else {
    const int n = ((role - 32) << 4) + (t >> 4);   // 0..31
    const int kl = t & 15;
    #pragma unroll
    for (int j = 0; j < 8; ++j) {
      const int k = (kl << 3) + j;
      ushort hi, lo;
      split2(wom[k * 32 + n], hi, lo);
      omh[n * 128 + k] = hi;
      oml[n * 128 + k] = lo;
    }
  }
}

// ---- wx: out[b][o][hw] = sum_c W[o][c]*act[b][c][hw] + bias[o], MFMA bf16-split ----
// block tile: 128 o (full) x 128 hw. grid (32, 8).
__global__ __launch_bounds__(256) void gemm_wx(
    const float* __restrict__ act, const ushort* __restrict__ Wh,
    const ushort* __restrict__ Wl, const float* __restrict__ bias,
    float* __restrict__ out)
{
  __shared__ __align__(16) ushort Ah[128][32], Al[128][32];   // [o][c-chunk]
  __shared__ __align__(16) ushort Bh[128][32], Bl[128][32];   // [hw-local][c-chunk]
  __shared__ float bias_s[128];
  const int t = threadIdx.x;
  const int hwBase = blockIdx.x << 7;
  const size_t base = (size_t)blockIdx.y * (size_t)(128 * HW);
  if (t < 128) bias_s[t] = bias[t];
  const int lane = t & 63, w = t >> 6;
  const int col = lane & 15, quad = lane >> 4;
  const int wm = (w & 1) << 6, wn = (w >> 1) << 6;
  const f32x4 z = {0.f, 0.f, 0.f, 0.f};
  f32x4 acc[4][4];
  #pragma unroll
  for (int i = 0; i < 4; ++i)
    #pragma unroll
    for (int j = 0; j < 4; ++j) acc[i][j] = z;

  for (int kc = 0; kc < 4; ++kc) {
    const int kBase = kc << 5;
    #pragma unroll
    for (int i = 0; i < 2; ++i) {
      const int idx = t + (i << 8);
      const int o = idx >> 2, q = (idx & 3) << 3;
      *(uint4*)&Ah[o][q] = *(const uint4*)&Wh[o * 128 + kBase + q];
      *(uint4*)&Al[o][q] = *(const uint4*)&Wl[o * 128 + kBase + q];
    }
    {
      const int kr = t >> 3, j0 = (t & 7) << 4;
      const float* srow = &act[base + (size_t)(kBase + kr) * HW + hwBase + j0];
      #pragma unroll
      for (int c4 = 0; c4 < 4; ++c4) {
        const float4 f = *(const float4*)(srow + (c4 << 2));
        ushort h0, l0, h1, l1, h2, l2, h3, l3;
        split2(f.x, h0, l0); split2(f.y, h1, l1);
        split2(f.z, h2, l2); split2(f.w, h3, l3);
        const int j = j0 + (c4 << 2);
        Bh[j + 0][kr] = h0; Bl[j + 0][kr] = l0;
        Bh[j + 1][kr] = h1; Bl[j + 1][kr] = l1;
        Bh[j + 2][kr] = h2; Bl[j + 2][kr] = l2;
        Bh[j + 3][kr] = h3; Bl[j + 3][kr] = l3;
      }
    }
    __syncthreads();
    short8 ah[4], al[4], bh[4], bl[4];
    #pragma unroll
    for (int f = 0; f < 4; ++f) {
      const int row = wm + (f << 4) + col;
      ah[f] = *(const short8*)&Ah[row][quad << 3];
      al[f] = *(const short8*)&Al[row][quad << 3];
    }
    #pragma unroll
    for (int g = 0; g < 4; ++g) {
      const int row = wn + (g << 4) + col;
      bh[g] = *(const short8*)&Bh[row][quad << 3];
      bl[g] = *(const short8*)&Bl[row][quad << 3];
    }
    #pragma unroll
    for (int f = 0; f < 4; ++f)
      #pragma unroll
      for (int g = 0; g < 4; ++g) {
        acc[f][g] = __builtin_amdgcn_mfma_f32_16x16x32_bf16(ah[f], bh[g], acc[f][g], 0, 0, 0);
        acc[f][g] = __builtin_amdgcn_mfma_f32_16x16x32_bf16(ah[f], bl[g], acc[f][g], 0, 0, 0);
        acc[f][g] = __builtin_amdgcn_mfma_f32_16x16x32_bf16(al[f], bh[g], acc[f][g], 0, 0, 0);
      }
    __syncthreads();
  }
  #pragma unroll
  for (int f = 0; f < 4; ++f)
    #pragma unroll
    for (int r = 0; r < 4; ++r) {
      const int o = wm + (f << 4) + (quad << 2) + r;
      const float bb = bias_s[o];
      #pragma unroll
      for (int g = 0; g < 4; ++g)
        out[base + (size_t)o * HW + hwBase + wn + (g << 4) + col] = acc[f][g][r] + bb;
    }
}

// ---- an: C[r][n] = sum_k A[r][k]*B[k][n]; A f32 row-major, B pre-split [n][k] ----
// VALOM: n<128 -> C1=value (+bias1), n>=128 -> C2=om (+bias2). grid (256).
template<int NF, bool VALOM>
__global__ __launch_bounds__(256) void gemm_an(
    const float* __restrict__ src,
    const ushort* __restrict__ BTh, const ushort* __restrict__ BTl,
    const ushort* __restrict__ BT2h, const ushort* __restrict__ BT2l,
    const float* __restrict__ bias1, const float* __restrict__ bias2,
    float* __restrict__ C1, float* __restrict__ C2)
{
  __shared__ __align__(16) ushort Ah[128][32], Al[128][32];
  __shared__ __align__(16) ushort Bh[NF * 32][32], Bl[NF * 32][32];
  const int t = threadIdx.x;
  const int rBase = blockIdx.x << 7;
  const int lane = t & 63, w = t >> 6;
  const int col = lane & 15, quad = lane >> 4;
  const int wm = (w & 1) << 6;
  const int wn = (w >> 1) * (NF * 16);
  const f32x4 z = {0.f, 0.f, 0.f, 0.f};
  f32x4 acc[4][NF];
  #pragma unroll
  for (int i = 0; i < 4; ++i)
    #pragma unroll
    for (int j = 0; j < NF; ++j) acc[i][j] = z;

  for (int kc = 0; kc < 4; ++kc) {
    const int kBase = kc << 5;
    {
      const int row = t >> 1, kh = (t & 1) << 4;
      const float* sr = &src[(size_t)(rBase + row) * 128 + kBase + kh];
      union { ushort u[8]; uint4 v; } ph, pl;
      #pragma unroll
      for (int half = 0; half < 2; ++half) {
        #pragma unroll
        for (int c4 = 0; c4 < 2; ++c4) {
          const float4 f = *(const float4*)(sr + (half << 3) + (c4 << 2));
          split2(f.x, ph.u[c4 * 4 + 0], pl.u[c4 * 4 + 0]);
          split2(f.y, ph.u[c4 * 4 + 1], pl.u[c4 * 4 + 1]);
          split2(f.z, ph.u[c4 * 4 + 2], pl.u[c4 * 4 + 2]);
          split2(f.w, ph.u[c4 * 4 + 3], pl.u[c4 * 4 + 3]);
        }
        *(uint4*)&Ah[row][kh + (half << 3)] = ph.v;
        *(uint4*)&Al[row][kh + (half << 3)] = pl.v;
      }
    }
    for (int i = t; i < NF * 32 * 4; i += 256) {
      const int n = i >> 2, q = (i & 3) << 3;
      const ushort* ph = (VALOM && n >= 128) ? &BT2h[(n - 128) * 128 + kBase + q]
                                             : &BTh[n * 128 + kBase + q];
      const ushort* pl = (VALOM && n >= 128) ? &BT2l[(n - 128) * 128 + kBase + q]
                                             : &BTl[n * 128 + kBase + q];
      *(uint4*)&Bh[n][q] = *(const uint4*)ph;
      *(uint4*)&Bl[n][q] = *(const uint4*)pl;
    }
    __syncthreads();
    short8 ah[4], al[4];
    #pragma unroll
    for (int f = 0; f < 4; ++f) {
      const int row = wm + (f << 4) + col;
      ah[f] = *(const short8*)&Ah[row][quad << 3];
      al[f] = *(const short8*)&Al[row][quad << 3];
    }
    #pragma unroll
    for (int g = 0; g < NF; ++g) {
      const int row = wn + (g << 4) + col;
      const short8 bh = *(const short8*)&Bh[row][quad << 3];
      const short8 bl = *(const short8*)&Bl[row][quad << 3];
      #pragma unroll
      for (int f = 0; f < 4; ++f) {
        acc[f][g] = __builtin_amdgcn_mfma_f32_16x16x32_bf16(ah[f], bh, acc[f][g], 0, 0, 0);
        acc[f][g] = __builtin_amdgcn_mfma_f32_16x16x32_bf16(ah[f], bl, acc[f][g], 0, 0, 0);
        acc[f][g] = __builtin_amdgcn_mfma_f32_16x16x32_bf16(al[f], bh, acc[f][g], 0, 0, 0);
      }
    }
    __syncthreads();
  }
  int ng[NF];
  float bb[NF];
  #pragma unroll
  for (int g = 0; g < NF; ++g) {
    ng[g] = wn + (g << 4) + col;
    bb[g] = VALOM ? (ng[g] < 128 ? bias1[ng[g]] : bias2[ng[g] - 128]) : 0.f;
  }
  #pragma unroll
  for (int f = 0; f < 4; ++f)
    #pragma unroll
    for (int r = 0; r < 4; ++r) {
      const int m = rBase + wm + (f << 4) + (quad << 2) + r;
      #pragma unroll
      for (int g = 0; g < NF; ++g) {
        const float v = acc[f][g][r] + bb[g];
        if (VALOM) {
          if (ng[g] < 128) C1[(size_t)m * 128 + ng[g]] = v;
          else             C2[(size_t)m * 32 + (ng[g] - 128)] = v;
        } else {
          C1[(size_t)m * 128 + ng[g]] = v;
        }
      }
    }
}

// ---------------- deformable bilinear sampling ----------------
__global__ __launch_bounds__(256) void dcn_sample(
    const float* __restrict__ value, const float* __restrict__ om,
    float* __restrict__ out)
{
  __shared__ float oms[8][32];
  const int t = threadIdx.x;
  const int blk = blockIdx.x;
  const int b = blk >> 9;
  const int sBase = (blk & 511) << 3;
  const int s = sBase + (t >> 5);
  const int cg = (t & 31) << 2;
  oms[t >> 5][t & 31] = om[((size_t)b * HW + sBase + (t >> 5)) * 32 + (t & 31)];
  __syncthreads();
  const int h = s >> 6, wq = s & 63;
  const float* vb = value + (size_t)b * HW * 128;
  const float* omp = oms[t >> 5];
  const float fw = (float)wq, fh = (float)h;
  float4 acc = {0.f, 0.f, 0.f, 0.f};
  #pragma unroll
  for (int k = 0; k < 9; ++k) {
    const float kx = (float)(k % 3 - 1);
    const float ky = (float)(k / 3 - 1);
    const float dx = omp[k * 3 + 0];
    const float dy = omp[k * 3 + 1];
    const float m  = omp[k * 3 + 2];
    const float px = fw + kx + dx;
    const float py = fh + ky + dy;
    const float x0f = floorf(px), y0f = floorf(py);
    const float fx = px - x0f, fy = py - y0f;
    const int ix = (int)x0f, iy = (int)y0f;
    #pragma unroll
    for (int cy = 0; cy < 2; ++cy) {
      const int yi = iy + cy;
      const float wy = cy ? fy : 1.f - fy;
      const float vy = (yi >= 0 && yi < 64) ? 1.f : 0.f;
      const int yc = min(max(yi, 0), 63);
      #pragma unroll
      for (int cx = 0; cx < 2; ++cx) {
        const int xi = ix + cx;
        const float wx = cx ? fx : 1.f - fx;
        const float vx = (xi >= 0 && xi < 64) ? 1.f : 0.f;
        const int xc = min(max(xi, 0), 63);
        const float wgt = wx * wy * vx * vy * m;
        const float4 v = *(const float4*)&vb[(size_t)(yc * 64 + xc) * 128 + cg];
        acc.x = fmaf(wgt, v.x, acc.x);
        acc.y = fmaf(wgt, v.y, acc.y);
        acc.z = fmaf(wgt, v.z, acc.z);
        acc.w = fmaf(wgt, v.w, acc.w);
      }
    }
  }
  *(float4*)&out[((size_t)b * HW + s) * 128 + cg] = acc;
}

extern "C" void kernel_launch(void* const* d_in, const int* in_sizes, int n_in,
                              void* d_out, int out_size, void* d_ws, size_t ws_size,
                              hipStream_t stream)
{
  const float* x    = (const float*)d_in[0];
  const float* g1   = (const float*)d_in[1];
  const float* be1  = (const float*)d_in[2];
  const float* m1   = (const float*)d_in[3];
  const float* v1   = (const float*)d_in[4];
  const float* wpw0 = (const float*)d_in[5];
  const float* wvp  = (const float*)d_in[6];
  const float* bvp  = (const float*)d_in[7];
  const float* womW = (const float*)d_in[8];
  const float* bom  = (const float*)d_in[9];
  const float* wop  = (const float*)d_in[10];
  const float* g2   = (const float*)d_in[11];
  const float* be2  = (const float*)d_in[12];
  const float* m2   = (const float*)d_in[13];
  const float* v2   = (const float*)d_in[14];
  const float* wpw1 = (const float*)d_in[15];

  char* ws = (char*)d_ws;
  float* y2    = (float*)(ws + 0);          // 16 MB (b,o,hw) flat == rows x 128
  float* samp  = (float*)(ws + 0);          // aliases y2 (dead after valom)
  float* value = (float*)(ws + 16777216);   // 16 MB
  float* out2  = (float*)(ws + 16777216);   // aliases value (dead after sample)
  float* omb   = (float*)(ws + 33554432);   //  4 MB
  size_t o = 37748736;
  ushort* W0h = (ushort*)(ws + o); o += 32768;
  ushort* W0l = (ushort*)(ws + o); o += 32768;
  ushort* W1h = (ushort*)(ws + o); o += 32768;
  ushort* W1l = (ushort*)(ws + o); o += 32768;
  ushort* vph = (ushort*)(ws + o); o += 32768;
  ushort* vpl = (ushort*)(ws + o); o += 32768;
  ushort* oph = (ushort*)(ws + o); o += 32768;
  ushort* opl = (ushort*)(ws + o); o += 32768;
  ushort* omh = (ushort*)(ws + o); o += 8192;
  ushort* oml = (ushort*)(ws + o); o += 8192;
  float*  b0  = (float*)(ws + o);  o += 512;
  float*  b1  = (float*)(ws + o);

  prep<<<34, 256, 0, stream>>>(g1, be1, m1, v1, wpw0, g2, be2, m2, v2, wpw1,
                               wvp, womW, wop,
                               W0h, W0l, b0, W1h, W1l, b1,
                               vph, vpl, oph, opl, omh, oml);
  gemm_wx<<<dim3(32, 8), 256, 0, stream>>>(x, W0h, W0l, b0, y2);
  gemm_an<5, true><<<dim3(256), 256, 0, stream>>>(y2, vph, vpl, omh, oml,
                                                  bvp, bom, value, omb);
  dcn_sample<<<dim3(4096), 256, 0, stream>>>(value, omb, samp);
  gemm_an<4, false><<<dim3(256), 256, 0, stream>>>(samp, oph, opl, nullptr, nullptr,
                                                   nullptr, nullptr, out2, nullptr);
  gemm_wx<<<dim3(32, 8), 256, 0, stream>>>(out2, W1h, W1l, b1, (float*)d_out);
}

// Round 6
// 155.992 us; speedup vs baseline: 1.5172x; 1.0886x over previous
//
#include <hip/hip_runtime.h>

#define HW 4096
#define PAD 33
typedef unsigned short ushort;
typedef __attribute__((ext_vector_type(8))) short short8;
typedef __attribute__((ext_vector_type(4))) float f32x4;

__device__ __forceinline__ ushort bf_rne(float f) {
  unsigned u = __float_as_uint(f);
  unsigned r = (u + 0x7fffu + ((u >> 16) & 1u)) >> 16;
  return (ushort)r;
}
__device__ __forceinline__ void split2(float f, ushort& hi, ushort& lo) {
  ushort h = bf_rne(f);
  float hf = __uint_as_float((unsigned)h << 16);
  hi = h;
  lo = bf_rne(f - hf);
}

// ---------------- prep: fold BN into pw weights, split everything to bf16 hi/lo ----
// roles: 0-7 W0 fold, 8-15 W1 fold, 16-23 wvp^T, 24-31 wop^T, 32-33 wom^T
__global__ __launch_bounds__(256) void prep(
    const float* __restrict__ g1, const float* __restrict__ be1,
    const float* __restrict__ m1, const float* __restrict__ v1,
    const float* __restrict__ w0,
    const float* __restrict__ g2, const float* __restrict__ be2,
    const float* __restrict__ m2, const float* __restrict__ v2,
    const float* __restrict__ w1,
    const float* __restrict__ wvp, const float* __restrict__ wom,
    const float* __restrict__ wop,
    ushort* __restrict__ W0h, ushort* __restrict__ W0l, float* __restrict__ b0,
    ushort* __restrict__ W1h, ushort* __restrict__ W1l, float* __restrict__ b1,
    ushort* __restrict__ vph, ushort* __restrict__ vpl,
    ushort* __restrict__ oph, ushort* __restrict__ opl,
    ushort* __restrict__ omh, ushort* __restrict__ oml)
{
  const int t = threadIdx.x;
  const int role = blockIdx.x;
  if (role < 16) {
    __shared__ float sc[128], sh[128], part[16][17];
    const int cv = role >> 3;
    const float* g  = cv ? g2 : g1;
    const float* be = cv ? be2 : be1;
    const float* mm = cv ? m2 : m1;
    const float* vv = cv ? v2 : v1;
    if (t < 128) {
      float s = g[t] / sqrtf(vv[t] + 1e-5f);
      sc[t] = s;
      sh[t] = be[t] - mm[t] * s;
    }
    __syncthreads();
    const float* ws = cv ? w1 : w0;
    ushort* dh = cv ? W1h : W0h;
    ushort* dl = cv ? W1l : W0l;
    float* bb  = cv ? b1 : b0;
    const int o = ((role & 7) << 4) + (t >> 4);
    const int kl = t & 15;
    float accb = 0.f;
    #pragma unroll
    for (int j = 0; j < 8; ++j) {
      const int k = (kl << 3) + j;
      const float wv = ws[o * 128 + k];
      ushort hi, lo;
      split2(wv * sc[k], hi, lo);
      dh[o * 128 + k] = hi;
      dl[o * 128 + k] = lo;
      accb = fmaf(wv, sh[k], accb);
    }
    part[t >> 4][kl] = accb;
    __syncthreads();
    if (kl == 0) {
      float s = 0.f;
      #pragma unroll
      for (int j = 0; j < 16; ++j) s += part[t >> 4][j];
      bb[o] = s;
    }
  } else if (role < 32) {
    const int rr = role & 7;
    const float* srcM = (role < 24) ? wvp : wop;
    ushort* dh = (role < 24) ? vph : oph;
    ushort* dl = (role < 24) ? vpl : opl;
    const int n = (rr << 4) + (t >> 4);
    const int kl = t & 15;
    #pragma unroll
    for (int j = 0; j < 8; ++j) {
      const int k = (kl << 3) + j;
      ushort hi, lo;
      split2(srcM[k * 128 + n], hi, lo);
      dh[n * 128 + k] = hi;
      dl[n * 128 + k] = lo;
    }
  } else {
    const int n = ((role - 32) << 4) + (t >> 4);   // 0..31
    const int kl = t & 15;
    #pragma unroll
    for (int j = 0; j < 8; ++j) {
      const int k = (kl << 3) + j;
      ushort hi, lo;
      split2(wom[k * 32 + n], hi, lo);
      omh[n * 128 + k] = hi;
      oml[n * 128 + k] = lo;
    }
  }
}

// ---------------- F1: x -(W0',b0)-> y2[o][hw-tile] -(reshape)-> tokens -(wvp|wom)->
// value, om. hw tile = [cb*128, cb*128+128): phase-1 C row o == token r = o*32+cb,
// feature k = hw - hwBase. grid (32, 8).
__global__ __launch_bounds__(256) void fused_x_valom(
    const float* __restrict__ x,
    const ushort* __restrict__ W0h, const ushort* __restrict__ W0l,
    const float* __restrict__ b0,
    const ushort* __restrict__ vph, const ushort* __restrict__ vpl,
    const float* __restrict__ bvp, const float* __restrict__ bom,
    float* __restrict__ value, float* __restrict__ omb)
{
  // phase1: Wh[128][32]@0, Wl@8192, Xf[128][33]@16384 (ends 33280)
  // phase2: Yf[128][33]@0 (ends 16896), Vh[160][32]@16896, Vl@27136 (ends 37376)
  __shared__ __align__(16) char smem[37376];
  __shared__ float b0_s[128], b2_s[160];
  ushort (*Wh_s)[32] = (ushort(*)[32])(smem);
  ushort (*Wl_s)[32] = (ushort(*)[32])(smem + 8192);
  float*  Xf         = (float*)(smem + 16384);
  float*  Yf         = (float*)(smem);
  ushort (*Vh_s)[32] = (ushort(*)[32])(smem + 16896);
  ushort (*Vl_s)[32] = (ushort(*)[32])(smem + 27136);

  const int t = threadIdx.x;
  const int cb = blockIdx.x;
  const int b = blockIdx.y;
  const int hwBase = cb << 7;
  const size_t xbase = (size_t)b * (size_t)(128 * HW);
  if (t < 128) b0_s[t] = b0[t];
  if (t < 160) b2_s[t] = (t < 128) ? bvp[t] : bom[t - 128];
  const int lane = t & 63, w = t >> 6;
  const int col = lane & 15, quad = lane >> 4;
  const int wm1 = (w & 1) << 6, wn1 = (w >> 1) << 6;
  const f32x4 z = {0.f, 0.f, 0.f, 0.f};

  // ---- phase 1: C[o=128][j=128] = W0'[o][c] * x[c][hwBase+j] ----
  f32x4 acc1[4][4];
  #pragma unroll
  for (int i = 0; i < 4; ++i)
    #pragma unroll
    for (int j = 0; j < 4; ++j) acc1[i][j] = z;

  for (int kc = 0; kc < 4; ++kc) {
    const int kB = kc << 5;
    for (int i = t; i < 512; i += 256) {
      const int o = i >> 2, q8 = (i & 3) << 3;
      *(uint4*)&Wh_s[o][q8] = *(const uint4*)&W0h[o * 128 + kB + q8];
      *(uint4*)&Wl_s[o][q8] = *(const uint4*)&W0l[o * 128 + kB + q8];
    }
    #pragma unroll
    for (int p = 0; p < 4; ++p) {
      const int idx = (p << 8) + t;
      const int c = idx >> 5, j4 = (idx & 31) << 2;
      const float4 f = *(const float4*)&x[xbase + (size_t)(kB + c) * HW + hwBase + j4];
      Xf[(j4 + 0) * PAD + c] = f.x;
      Xf[(j4 + 1) * PAD + c] = f.y;
      Xf[(j4 + 2) * PAD + c] = f.z;
      Xf[(j4 + 3) * PAD + c] = f.w;
    }
    __syncthreads();
    short8 aH[4], aL[4];
    #pragma unroll
    for (int f = 0; f < 4; ++f) {
      const int row = wm1 + (f << 4) + col;
      aH[f] = *(const short8*)&Wh_s[row][quad << 3];
      aL[f] = *(const short8*)&Wl_s[row][quad << 3];
    }
    #pragma unroll
    for (int g = 0; g < 4; ++g) {
      const float* xr = &Xf[(wn1 + (g << 4) + col) * PAD + (quad << 3)];
      union { ushort u[8]; short8 v; } bh, bl;
      #pragma unroll
      for (int j = 0; j < 8; ++j) split2(xr[j], bh.u[j], bl.u[j]);
      #pragma unroll
      for (int f = 0; f < 4; ++f) {
        acc1[f][g] = __builtin_amdgcn_mfma_f32_16x16x32_bf16(aH[f], bh.v, acc1[f][g], 0, 0, 0);
        acc1[f][g] = __builtin_amdgcn_mfma_f32_16x16x32_bf16(aH[f], bl.v, acc1[f][g], 0, 0, 0);
        acc1[f][g] = __builtin_amdgcn_mfma_f32_16x16x32_bf16(aL[f], bh.v, acc1[f][g], 0, 0, 0);
      }
    }
    __syncthreads();
  }

  // ---- phase 2: [value|om][m=128 tokens][n=160], contraction k = j (hw-local) ----
  const int wm2 = (w & 1) << 6;
  const int wn2 = (w >> 1) * 80;
  f32x4 acc2[4][5];
  #pragma unroll
  for (int i = 0; i < 4; ++i)
    #pragma unroll
    for (int j = 0; j < 5; ++j) acc2[i][j] = z;

  for (int j2 = 0; j2 < 4; ++j2) {
    for (int i = t; i < 640; i += 256) {
      const int n = i >> 2, q8 = (i & 3) << 3;
      *(uint4*)&Vh_s[n][q8] = *(const uint4*)&vph[n * 128 + (j2 << 5) + q8];
      *(uint4*)&Vl_s[n][q8] = *(const uint4*)&vpl[n * 128 + (j2 << 5) + q8];
    }
    // scatter chunk j2 (j in [j2*32, j2*32+32)) of phase-1 C into Yf[m=o][jl], +bias
    if ((w >> 1) == (j2 >> 1)) {
      #pragma unroll
      for (int gg = 0; gg < 2; ++gg) {
        const int g = ((j2 & 1) << 1) + gg;
        #pragma unroll
        for (int f = 0; f < 4; ++f) {
          const int o = wm1 + (f << 4) + (quad << 2);
          #pragma unroll
          for (int r = 0; r < 4; ++r)
            Yf[(o + r) * PAD + (gg << 4) + col] = acc1[f][g][r] + b0_s[o + r];
        }
      }
    }
    __syncthreads();
    union { ushort u[8]; short8 v; } a2h[4], a2l[4];
    #pragma unroll
    for (int f2 = 0; f2 < 4; ++f2) {
      const float* yr = &Yf[(wm2 + (f2 << 4) + col) * PAD + (quad << 3)];
      #pragma unroll
      for (int j = 0; j < 8; ++j) split2(yr[j], a2h[f2].u[j], a2l[f2].u[j]);
    }
    #pragma unroll
    for (int g2 = 0; g2 < 5; ++g2) {
      const int n = wn2 + (g2 << 4) + col;
      const short8 vh = *(const short8*)&Vh_s[n][quad << 3];
      const short8 vl = *(const short8*)&Vl_s[n][quad << 3];
      #pragma unroll
      for (int f2 = 0; f2 < 4; ++f2) {
        acc2[f2][g2] = __builtin_amdgcn_mfma_f32_16x16x32_bf16(a2h[f2].v, vh, acc2[f2][g2], 0, 0, 0);
        acc2[f2][g2] = __builtin_amdgcn_mfma_f32_16x16x32_bf16(a2h[f2].v, vl, acc2[f2][g2], 0, 0, 0);
        acc2[f2][g2] = __builtin_amdgcn_mfma_f32_16x16x32_bf16(a2l[f2].v, vh, acc2[f2][g2], 0, 0, 0);
      }
    }
    __syncthreads();
  }
  #pragma unroll
  for (int f2 = 0; f2 < 4; ++f2)
    #pragma unroll
    for (int r = 0; r < 4; ++r) {
      const int m = wm2 + (f2 << 4) + (quad << 2) + r;
      const size_t gRow = (size_t)b * HW + (size_t)m * 32 + cb;   // token r = m*32+cb
      #pragma unroll
      for (int g2 = 0; g2 < 5; ++g2) {
        const int n = wn2 + (g2 << 4) + col;
        const float v = acc2[f2][g2][r] + b2_s[n];
        if (n < 128) value[gRow * 128 + n] = v;
        else         omb[gRow * 32 + (n - 128)] = v;
      }
    }
}

// ---------------- deformable bilinear sampling -> pre-split bf16 hi/lo ----------------
__global__ __launch_bounds__(256) void dcn_sample(
    const float* __restrict__ value, const float* __restrict__ om,
    ushort* __restrict__ samph, ushort* __restrict__ sampl)
{
  __shared__ float oms[8][32];
  const int t = threadIdx.x;
  const int blk = blockIdx.x;
  const int b = blk >> 9;
  const int sBase = (blk & 511) << 3;
  const int s = sBase + (t >> 5);
  const int cg = (t & 31) << 2;
  oms[t >> 5][t & 31] = om[((size_t)b * HW + sBase + (t >> 5)) * 32 + (t & 31)];
  __syncthreads();
  const int h = s >> 6, wq = s & 63;
  const float* vb = value + (size_t)b * HW * 128;
  const float* omp = oms[t >> 5];
  const float fw = (float)wq, fh = (float)h;
  float4 acc = {0.f, 0.f, 0.f, 0.f};
  #pragma unroll
  for (int k = 0; k < 9; ++k) {
    const float kx = (float)(k % 3 - 1);
    const float ky = (float)(k / 3 - 1);
    const float dx = omp[k * 3 + 0];
    const float dy = omp[k * 3 + 1];
    const float m  = omp[k * 3 + 2];
    const float px = fw + kx + dx;
    const float py = fh + ky + dy;
    const float x0f = floorf(px), y0f = floorf(py);
    const float fx = px - x0f, fy = py - y0f;
    const int ix = (int)x0f, iy = (int)y0f;
    #pragma unroll
    for (int cy = 0; cy < 2; ++cy) {
      const int yi = iy + cy;
      const float wy = cy ? fy : 1.f - fy;
      const float vy = (yi >= 0 && yi < 64) ? 1.f : 0.f;
      const int yc = min(max(yi, 0), 63);
      #pragma unroll
      for (int cx = 0; cx < 2; ++cx) {
        const int xi = ix + cx;
        const float wx = cx ? fx : 1.f - fx;
        const float vx = (xi >= 0 && xi < 64) ? 1.f : 0.f;
        const int xc = min(max(xi, 0), 63);
        const float wgt = wx * wy * vx * vy * m;
        const float4 v = *(const float4*)&vb[(size_t)(yc * 64 + xc) * 128 + cg];
        acc.x = fmaf(wgt, v.x, acc.x);
        acc.y = fmaf(wgt, v.y, acc.y);
        acc.z = fmaf(wgt, v.z, acc.z);
        acc.w = fmaf(wgt, v.w, acc.w);
      }
    }
  }
  ushort h0, l0, h1, l1, h2, l2, h3, l3;
  split2(acc.x, h0, l0); split2(acc.y, h1, l1);
  split2(acc.z, h2, l2); split2(acc.w, h3, l3);
  const size_t idx = ((size_t)b * HW + s) * 128 + cg;
  uint2 uh, ul;
  uh.x = (unsigned)h0 | ((unsigned)h1 << 16);
  uh.y = (unsigned)h2 | ((unsigned)h3 << 16);
  ul.x = (unsigned)l0 | ((unsigned)l1 << 16);
  ul.y = (unsigned)l2 | ((unsigned)l3 << 16);
  *(uint2*)&samph[idx] = uh;
  *(uint2*)&sampl[idx] = ul;
}

// ---------------- F2: samp rows {m*32+cb} -(wop)-> xnew[ch][hwBase+j] -(W1',b1)-> out
// grid (32, 8). Phase-1 C[m=ch][c2=j]; phase-2 contracts over ch (phase-1 M).
__global__ __launch_bounds__(256) void fused_op_out(
    const ushort* __restrict__ samph, const ushort* __restrict__ sampl,
    const ushort* __restrict__ oph, const ushort* __restrict__ opl,
    const ushort* __restrict__ W1h, const ushort* __restrict__ W1l,
    const float* __restrict__ b1, float* __restrict__ out)
{
  // phase1: Ah@0, Al@8192, Bh@16384, Bl@24576 (ends 32768)
  // phase2: Yf[128][33]@0 (ends 16896), W1h_s@16896, W1l_s@25088 (ends 33280)
  __shared__ __align__(16) char smem[33280];
  __shared__ float b1_s[128];
  ushort (*Ah_s)[32]  = (ushort(*)[32])(smem);
  ushort (*Al_s)[32]  = (ushort(*)[32])(smem + 8192);
  ushort (*Bh_s)[32]  = (ushort(*)[32])(smem + 16384);
  ushort (*Bl_s)[32]  = (ushort(*)[32])(smem + 24576);
  float*  Yf          = (float*)(smem);
  ushort (*W1h_s)[32] = (ushort(*)[32])(smem + 16896);
  ushort (*W1l_s)[32] = (ushort(*)[32])(smem + 25088);

  const int t = threadIdx.x;
  const int cb = blockIdx.x;
  const int b = blockIdx.y;
  if (t < 128) b1_s[t] = b1[t];
  const int lane = t & 63, w = t >> 6;
  const int col = lane & 15, quad = lane >> 4;
  const int wm1 = (w & 1) << 6, wn1 = (w >> 1) << 6;
  const f32x4 z = {0.f, 0.f, 0.f, 0.f};

  // ---- phase 1: C[m=ch=128][j=128] = samp[{m*32+cb}][k] * wop'[j][k] ----
  f32x4 acc1[4][4];
  #pragma unroll
  for (int i = 0; i < 4; ++i)
    #pragma unroll
    for (int j = 0; j < 4; ++j) acc1[i][j] = z;

  for (int kc = 0; kc < 4; ++kc) {
    const int kB = kc << 5;
    for (int i = t; i < 512; i += 256) {
      const int m = i >> 2, q8 = (i & 3) << 3;
      const size_t row = (size_t)b * HW + (size_t)m * 32 + cb;
      *(uint4*)&Ah_s[m][q8] = *(const uint4*)&samph[row * 128 + kB + q8];
      *(uint4*)&Al_s[m][q8] = *(const uint4*)&sampl[row * 128 + kB + q8];
      *(uint4*)&Bh_s[m][q8] = *(const uint4*)&oph[m * 128 + kB + q8];
      *(uint4*)&Bl_s[m][q8] = *(const uint4*)&opl[m * 128 + kB + q8];
    }
    __syncthreads();
    short8 aH[4], aL[4];
    #pragma unroll
    for (int f = 0; f < 4; ++f) {
      const int row = wm1 + (f << 4) + col;
      aH[f] = *(const short8*)&Ah_s[row][quad << 3];
      aL[f] = *(const short8*)&Al_s[row][quad << 3];
    }
    #pragma unroll
    for (int g = 0; g < 4; ++g) {
      const int n = wn1 + (g << 4) + col;
      const short8 bh = *(const short8*)&Bh_s[n][quad << 3];
      const short8 bl = *(const short8*)&Bl_s[n][quad << 3];
      #pragma unroll
      for (int f = 0; f < 4; ++f) {
        acc1[f][g] = __builtin_amdgcn_mfma_f32_16x16x32_bf16(aH[f], bh, acc1[f][g], 0, 0, 0);
        acc1[f][g] = __builtin_amdgcn_mfma_f32_16x16x32_bf16(aH[f], bl, acc1[f][g], 0, 0, 0);
        acc1[f][g] = __builtin_amdgcn_mfma_f32_16x16x32_bf16(aL[f], bh, acc1[f][g], 0, 0, 0);
      }
    }
    __syncthreads();
  }

  // ---- phase 2: out[o=128][j=128] = W1'[o][ch] * C[ch][j], ch chunks of 32 ----
  const int wm2 = (w & 1) << 6, wn2 = (w >> 1) << 6;
  f32x4 acc2[4][4];
  #pragma unroll
  for (int i = 0; i < 4; ++i)
    #pragma unroll
    for (int j = 0; j < 4; ++j) acc2[i][j] = z;

  for (int j2 = 0; j2 < 4; ++j2) {
    for (int i = t; i < 512; i += 256) {
      const int o = i >> 2, q8 = (i & 3) << 3;
      *(uint4*)&W1h_s[o][q8] = *(const uint4*)&W1h[o * 128 + (j2 << 5) + q8];
      *(uint4*)&W1l_s[o][q8] = *(const uint4*)&W1l[o * 128 + (j2 << 5) + q8];
    }
    // scatter ch chunk j2 of phase-1 C into Yf[j][ch_local]
    if ((w & 1) == (j2 >> 1)) {
      #pragma unroll
      for (int ff = 0; ff < 2; ++ff) {
        const int f = ((j2 & 1) << 1) + ff;
        #pragma unroll
        for (int g = 0; g < 4; ++g) {
          const int j = wn1 + (g << 4) + col;
          #pragma unroll
          for (int r = 0; r < 4; ++r)
            Yf[j * PAD + (ff << 4) + (quad << 2) + r] = acc1[f][g][r];
        }
      }
    }
    __syncthreads();
    union { ushort u[8]; short8 v; } b5h[4], b5l[4];
    #pragma unroll
    for (int g2 = 0; g2 < 4; ++g2) {
      const float* yr = &Yf[(wn2 + (g2 << 4) + col) * PAD + (quad << 3)];
      #pragma unroll
      for (int j = 0; j < 8; ++j) split2(yr[j], b5h[g2].u[j], b5l[g2].u[j]);
    }
    #pragma unroll
    for (int f2 = 0; f2 < 4; ++f2) {
      const int o = wm2 + (f2 << 4) + col;
      const short8 ah = *(const short8*)&W1h_s[o][quad << 3];
      const short8 al = *(const short8*)&W1l_s[o][quad << 3];
      #pragma unroll
      for (int g2 = 0; g2 < 4; ++g2) {
        acc2[f2][g2] = __builtin_amdgcn_mfma_f32_16x16x32_bf16(ah, b5h[g2].v, acc2[f2][g2], 0, 0, 0);
        acc2[f2][g2] = __builtin_amdgcn_mfma_f32_16x16x32_bf16(ah, b5l[g2].v, acc2[f2][g2], 0, 0, 0);
        acc2[f2][g2] = __builtin_amdgcn_mfma_f32_16x16x32_bf16(al, b5h[g2].v, acc2[f2][g2], 0, 0, 0);
      }
    }
    __syncthreads();
  }
  const size_t obase = (size_t)b * (size_t)(128 * HW) + ((size_t)cb << 7);
  #pragma unroll
  for (int f2 = 0; f2 < 4; ++f2)
    #pragma unroll
    for (int r = 0; r < 4; ++r) {
      const int o = wm2 + (f2 << 4) + (quad << 2) + r;
      #pragma unroll
      for (int g2 = 0; g2 < 4; ++g2) {
        const int j = wn2 + (g2 << 4) + col;
        out[obase + (size_t)o * HW + j] = acc2[f2][g2][r] + b1_s[o];
      }
    }
}

extern "C" void kernel_launch(void* const* d_in, const int* in_sizes, int n_in,
                              void* d_out, int out_size, void* d_ws, size_t ws_size,
                              hipStream_t stream)
{
  const float* x    = (const float*)d_in[0];
  const float* g1   = (const float*)d_in[1];
  const float* be1  = (const float*)d_in[2];
  const float* m1   = (const float*)d_in[3];
  const float* v1   = (const float*)d_in[4];
  const float* wpw0 = (const float*)d_in[5];
  const float* wvp  = (const float*)d_in[6];
  const float* bvp  = (const float*)d_in[7];
  const float* womW = (const float*)d_in[8];
  const float* bom  = (const float*)d_in[9];
  const float* wop  = (const float*)d_in[10];
  const float* g2   = (const float*)d_in[11];
  const float* be2  = (const float*)d_in[12];
  const float* m2   = (const float*)d_in[13];
  const float* v2   = (const float*)d_in[14];
  const float* wpw1 = (const float*)d_in[15];

  char* ws = (char*)d_ws;
  float*  value = (float*) (ws + 0);          // 16 MB (b,s,cg) f32
  float*  omb   = (float*) (ws + 16777216);   //  4 MB (b,s,32) f32
  ushort* samph = (ushort*)(ws + 20971520);   //  8 MB
  ushort* sampl = (ushort*)(ws + 29360128);   //  8 MB
  size_t o = 37748736;
  ushort* W0h = (ushort*)(ws + o); o += 32768;
  ushort* W0l = (ushort*)(ws + o); o += 32768;
  ushort* W1h = (ushort*)(ws + o); o += 32768;
  ushort* W1l = (ushort*)(ws + o); o += 32768;
  ushort* vph = (ushort*)(ws + o); o += 40960;  // 160 x 128 (value 128 rows + om 32 rows)
  ushort* vpl = (ushort*)(ws + o); o += 40960;
  ushort* oph = (ushort*)(ws + o); o += 32768;
  ushort* opl = (ushort*)(ws + o); o += 32768;
  float*  b0  = (float*)(ws + o);  o += 512;
  float*  b1  = (float*)(ws + o);
  ushort* omh = vph + 128 * 128;   // om rows live at n = 128..159 of the V matrix
  ushort* oml = vpl + 128 * 128;

  prep<<<34, 256, 0, stream>>>(g1, be1, m1, v1, wpw0, g2, be2, m2, v2, wpw1,
                               wvp, womW, wop,
                               W0h, W0l, b0, W1h, W1l, b1,
                               vph, vpl, oph, opl, omh, oml);
  fused_x_valom<<<dim3(32, 8), 256, 0, stream>>>(x, W0h, W0l, b0, vph, vpl,
                                                 bvp, bom, value, omb);
  dcn_sample<<<dim3(4096), 256, 0, stream>>>(value, omb, samph, sampl);
  fused_op_out<<<dim3(32, 8), 256, 0, stream>>>(samph, sampl, oph, opl,
                                                W1h, W1l, b1, (float*)d_out);
}

// Round 7
// 148.241 us; speedup vs baseline: 1.5966x; 1.0523x over previous
//
#include <hip/hip_runtime.h>

#define HW 4096
#define PADF 33      // f32 row stride for Xf
#define PADU 136     // ushort row stride for Y tiles (272 B, 16B-aligned)
typedef unsigned short ushort;
typedef __attribute__((ext_vector_type(8))) short short8;
typedef __attribute__((ext_vector_type(4))) float f32x4;

__device__ __forceinline__ ushort bf_rne(float f) {
  unsigned u = __float_as_uint(f);
  unsigned r = (u + 0x7fffu + ((u >> 16) & 1u)) >> 16;
  return (ushort)r;
}
__device__ __forceinline__ void split2(float f, ushort& hi, ushort& lo) {
  ushort h = bf_rne(f);
  float hf = __uint_as_float((unsigned)h << 16);
  hi = h;
  lo = bf_rne(f - hf);
}

// ---------------- prep: fold BN into pw weights, split everything to bf16 hi/lo ----
// roles: 0-7 W0 fold, 8-15 W1 fold, 16-23 wvp^T, 24-31 wop^T, 32-33 wom^T
__global__ __launch_bounds__(256) void prep(
    const float* __restrict__ g1, const float* __restrict__ be1,
    const float* __restrict__ m1, const float* __restrict__ v1,
    const float* __restrict__ w0,
    const float* __restrict__ g2, const float* __restrict__ be2,
    const float* __restrict__ m2, const float* __restrict__ v2,
    const float* __restrict__ w1,
    const float* __restrict__ wvp, const float* __restrict__ wom,
    const float* __restrict__ wop,
    ushort* __restrict__ W0h, ushort* __restrict__ W0l, float* __restrict__ b0,
    ushort* __restrict__ W1h, ushort* __restrict__ W1l, float* __restrict__ b1,
    ushort* __restrict__ vph, ushort* __restrict__ vpl,
    ushort* __restrict__ oph, ushort* __restrict__ opl,
    ushort* __restrict__ omh, ushort* __restrict__ oml)
{
  const int t = threadIdx.x;
  const int role = blockIdx.x;
  if (role < 16) {
    __shared__ float sc[128], sh[128], part[16][17];
    const int cv = role >> 3;
    const float* g  = cv ? g2 : g1;
    const float* be = cv ? be2 : be1;
    const float* mm = cv ? m2 : m1;
    const float* vv = cv ? v2 : v1;
    if (t < 128) {
      float s = g[t] / sqrtf(vv[t] + 1e-5f);
      sc[t] = s;
      sh[t] = be[t] - mm[t] * s;
    }
    __syncthreads();
    const float* ws = cv ? w1 : w0;
    ushort* dh = cv ? W1h : W0h;
    ushort* dl = cv ? W1l : W0l;
    float* bb  = cv ? b1 : b0;
    const int o = ((role & 7) << 4) + (t >> 4);
    const int kl = t & 15;
    float accb = 0.f;
    #pragma unroll
    for (int j = 0; j < 8; ++j) {
      const int k = (kl << 3) + j;
      const float wv = ws[o * 128 + k];
      ushort hi, lo;
      split2(wv * sc[k], hi, lo);
      dh[o * 128 + k] = hi;
      dl[o * 128 + k] = lo;
      accb = fmaf(wv, sh[k], accb);
    }
    part[t >> 4][kl] = accb;
    __syncthreads();
    if (kl == 0) {
      float s = 0.f;
      #pragma unroll
      for (int j = 0; j < 16; ++j) s += part[t >> 4][j];
      bb[o] = s;
    }
  } else if (role < 32) {
    const int rr = role & 7;
    const float* srcM = (role < 24) ? wvp : wop;
    ushort* dh = (role < 24) ? vph : oph;
    ushort* dl = (role < 24) ? vpl : opl;
    const int n = (rr << 4) + (t >> 4);
    const int kl = t & 15;
    #pragma unroll
    for (int j = 0; j < 8; ++j) {
      const int k = (kl << 3) + j;
      ushort hi, lo;
      split2(srcM[k * 128 + n], hi, lo);
      dh[n * 128 + k] = hi;
      dl[n * 128 + k] = lo;
    }
  } else {
    const int n = ((role - 32) << 4) + (t >> 4);   // 0..31
    const int kl = t & 15;
    #pragma unroll
    for (int j = 0; j < 8; ++j) {
      const int k = (kl << 3) + j;
      ushort hi, lo;
      split2(wom[k * 32 + n], hi, lo);
      omh[n * 128 + k] = hi;
      oml[n * 128 + k] = lo;
    }
  }
}

// ---------------- F1: x -(W0',b0)-> y2 tile -(reshape)-> tokens -(wvp|wom)-> value,om
// grid (32, 8), 512 thr (8 waves). Token r = o*32+cb, feature k = hw - cb*128.
__global__ __launch_bounds__(512, 2) void fused_x_valom(
    const float* __restrict__ x,
    const ushort* __restrict__ W0h, const ushort* __restrict__ W0l,
    const float* __restrict__ b0,
    const ushort* __restrict__ vph, const ushort* __restrict__ vpl,
    const float* __restrict__ bvp, const float* __restrict__ bom,
    float* __restrict__ value, float* __restrict__ omb)
{
  // region A (0..33279): phase1 Wh@0(8192) Wl@8192 Xf@16384(16896 B)
  //                      phase2 Vh@0(10240) Vl@10240
  // region B: Yh@33280(34816) Yl@68096(34816)  -> total 102912
  __shared__ __align__(16) char smem[102912];
  __shared__ float b0_s[128], b2_s[160];
  ushort (*Wh_s)[32] = (ushort(*)[32])(smem);
  ushort (*Wl_s)[32] = (ushort(*)[32])(smem + 8192);
  float*  Xf         = (float*)(smem + 16384);
  ushort (*Vh_s)[32] = (ushort(*)[32])(smem);
  ushort (*Vl_s)[32] = (ushort(*)[32])(smem + 10240);
  ushort (*Yh)[PADU] = (ushort(*)[PADU])(smem + 33280);
  ushort (*Yl)[PADU] = (ushort(*)[PADU])(smem + 68096);

  const int t = threadIdx.x;
  const int cb = blockIdx.x;
  const int b = blockIdx.y;
  const int hwBase = cb << 7;
  const size_t xbase = (size_t)b * (size_t)(128 * HW);
  if (t < 128) b0_s[t] = b0[t];
  if (t < 160) b2_s[t] = (t < 128) ? bvp[t] : bom[t - 128];
  const int lane = t & 63, w = t >> 6;          // 8 waves
  const int col = lane & 15, quad = lane >> 4;
  const f32x4 z = {0.f, 0.f, 0.f, 0.f};

  // ---- phase 1: C[o=128][j=128]; wave w owns j-strip [w*16, w*16+16) ----
  f32x4 acc1[8];
  #pragma unroll
  for (int f = 0; f < 8; ++f) acc1[f] = z;

  for (int kc = 0; kc < 4; ++kc) {
    const int kB = kc << 5;
    {
      const int o = t >> 2, q8 = (t & 3) << 3;
      *(uint4*)&Wh_s[o][q8] = *(const uint4*)&W0h[o * 128 + kB + q8];
      *(uint4*)&Wl_s[o][q8] = *(const uint4*)&W0l[o * 128 + kB + q8];
    }
    #pragma unroll
    for (int p = 0; p < 2; ++p) {
      const int idx = (p << 9) + t;
      const int c = idx >> 5, j4 = (idx & 31) << 2;
      const float4 f = *(const float4*)&x[xbase + (size_t)(kB + c) * HW + hwBase + j4];
      Xf[(j4 + 0) * PADF + c] = f.x;
      Xf[(j4 + 1) * PADF + c] = f.y;
      Xf[(j4 + 2) * PADF + c] = f.z;
      Xf[(j4 + 3) * PADF + c] = f.w;
    }
    __syncthreads();
    union { ushort u[8]; short8 v; } bh, bl;
    {
      const float* xr = &Xf[((w << 4) + col) * PADF + (quad << 3)];
      #pragma unroll
      for (int j = 0; j < 8; ++j) split2(xr[j], bh.u[j], bl.u[j]);
    }
    #pragma unroll
    for (int f = 0; f < 8; ++f) {
      const int row = (f << 4) + col;
      const short8 aH = *(const short8*)&Wh_s[row][quad << 3];
      const short8 aL = *(const short8*)&Wl_s[row][quad << 3];
      acc1[f] = __builtin_amdgcn_mfma_f32_16x16x32_bf16(aH, bh.v, acc1[f], 0, 0, 0);
      acc1[f] = __builtin_amdgcn_mfma_f32_16x16x32_bf16(aH, bl.v, acc1[f], 0, 0, 0);
      acc1[f] = __builtin_amdgcn_mfma_f32_16x16x32_bf16(aL, bh.v, acc1[f], 0, 0, 0);
    }
    __syncthreads();
  }

  // scatter y2 (+bias) pre-split into Yh/Yl[token o][feature j]
  #pragma unroll
  for (int f = 0; f < 8; ++f)
    #pragma unroll
    for (int r = 0; r < 4; ++r) {
      const int o = (f << 4) + (quad << 2) + r;
      const int j = (w << 4) + col;
      ushort hi, lo;
      split2(acc1[f][r] + b0_s[o], hi, lo);
      Yh[o][j] = hi;
      Yl[o][j] = lo;
    }

  // ---- phase 2: [value|om][m=128 tokens][n=160]; waves: 4 m-strips x 2 n-halves ----
  const int wm2 = (w & 3) << 5;
  const int wn2 = (w >> 2) * 80;
  f32x4 acc2[2][5];
  #pragma unroll
  for (int i = 0; i < 2; ++i)
    #pragma unroll
    for (int j = 0; j < 5; ++j) acc2[i][j] = z;

  for (int j2 = 0; j2 < 4; ++j2) {
    for (int i = t; i < 640; i += 512) {
      const int n = i >> 2, q8 = (i & 3) << 3;
      *(uint4*)&Vh_s[n][q8] = *(const uint4*)&vph[n * 128 + (j2 << 5) + q8];
      *(uint4*)&Vl_s[n][q8] = *(const uint4*)&vpl[n * 128 + (j2 << 5) + q8];
    }
    __syncthreads();
    short8 aH[2], aL[2];
    #pragma unroll
    for (int f2 = 0; f2 < 2; ++f2) {
      const int row = wm2 + (f2 << 4) + col;
      aH[f2] = *(const short8*)&Yh[row][(j2 << 5) + (quad << 3)];
      aL[f2] = *(const short8*)&Yl[row][(j2 << 5) + (quad << 3)];
    }
    #pragma unroll
    for (int g2 = 0; g2 < 5; ++g2) {
      const int n = wn2 + (g2 << 4) + col;
      const short8 vh = *(const short8*)&Vh_s[n][quad << 3];
      const short8 vl = *(const short8*)&Vl_s[n][quad << 3];
      #pragma unroll
      for (int f2 = 0; f2 < 2; ++f2) {
        acc2[f2][g2] = __builtin_amdgcn_mfma_f32_16x16x32_bf16(aH[f2], vh, acc2[f2][g2], 0, 0, 0);
        acc2[f2][g2] = __builtin_amdgcn_mfma_f32_16x16x32_bf16(aH[f2], vl, acc2[f2][g2], 0, 0, 0);
        acc2[f2][g2] = __builtin_amdgcn_mfma_f32_16x16x32_bf16(aL[f2], vh, acc2[f2][g2], 0, 0, 0);
      }
    }
    __syncthreads();
  }
  #pragma unroll
  for (int f2 = 0; f2 < 2; ++f2)
    #pragma unroll
    for (int r = 0; r < 4; ++r) {
      const int m = wm2 + (f2 << 4) + (quad << 2) + r;
      const size_t gRow = (size_t)b * HW + (size_t)m * 32 + cb;
      #pragma unroll
      for (int g2 = 0; g2 < 5; ++g2) {
        const int n = wn2 + (g2 << 4) + col;
        const float v = acc2[f2][g2][r] + b2_s[n];
        if (n < 128) value[gRow * 128 + n] = v;
        else         omb[gRow * 32 + (n - 128)] = v;
      }
    }
}

// ---------------- deformable bilinear sampling -> pre-split bf16 hi/lo ----------------
// b = blk&7: batch<->XCD affinity (round-robin dispatch) keeps value (2 MB) in one L2
__global__ __launch_bounds__(256) void dcn_sample(
    const float* __restrict__ value, const float* __restrict__ om,
    ushort* __restrict__ samph, ushort* __restrict__ sampl)
{
  __shared__ float oms[8][32];
  const int t = threadIdx.x;
  const int blk = blockIdx.x;
  const int b = blk & 7;
  const int sBase = (blk >> 3) << 3;
  const int s = sBase + (t >> 5);
  const int cg = (t & 31) << 2;
  oms[t >> 5][t & 31] = om[((size_t)b * HW + sBase + (t >> 5)) * 32 + (t & 31)];
  __syncthreads();
  const int h = s >> 6, wq = s & 63;
  const float* vb = value + (size_t)b * HW * 128;
  const float* omp = oms[t >> 5];
  const float fw = (float)wq, fh = (float)h;
  float4 acc = {0.f, 0.f, 0.f, 0.f};
  #pragma unroll
  for (int k = 0; k < 9; ++k) {
    const float kx = (float)(k % 3 - 1);
    const float ky = (float)(k / 3 - 1);
    const float dx = omp[k * 3 + 0];
    const float dy = omp[k * 3 + 1];
    const float m  = omp[k * 3 + 2];
    const float px = fw + kx + dx;
    const float py = fh + ky + dy;
    const float x0f = floorf(px), y0f = floorf(py);
    const float fx = px - x0f, fy = py - y0f;
    const int ix = (int)x0f, iy = (int)y0f;
    #pragma unroll
    for (int cy = 0; cy < 2; ++cy) {
      const int yi = iy + cy;
      const float wy = cy ? fy : 1.f - fy;
      const float vy = (yi >= 0 && yi < 64) ? 1.f : 0.f;
      const int yc = min(max(yi, 0), 63);
      #pragma unroll
      for (int cx = 0; cx < 2; ++cx) {
        const int xi = ix + cx;
        const float wx = cx ? fx : 1.f - fx;
        const float vx = (xi >= 0 && xi < 64) ? 1.f : 0.f;
        const int xc = min(max(xi, 0), 63);
        const float wgt = wx * wy * vx * vy * m;
        const float4 v = *(const float4*)&vb[(size_t)(yc * 64 + xc) * 128 + cg];
        acc.x = fmaf(wgt, v.x, acc.x);
        acc.y = fmaf(wgt, v.y, acc.y);
        acc.z = fmaf(wgt, v.z, acc.z);
        acc.w = fmaf(wgt, v.w, acc.w);
      }
    }
  }
  ushort h0, l0, h1, l1, h2, l2, h3, l3;
  split2(acc.x, h0, l0); split2(acc.y, h1, l1);
  split2(acc.z, h2, l2); split2(acc.w, h3, l3);
  const size_t idx = ((size_t)b * HW + s) * 128 + cg;
  uint2 uh, ul;
  uh.x = (unsigned)h0 | ((unsigned)h1 << 16);
  uh.y = (unsigned)h2 | ((unsigned)h3 << 16);
  ul.x = (unsigned)l0 | ((unsigned)l1 << 16);
  ul.y = (unsigned)l2 | ((unsigned)l3 << 16);
  *(uint2*)&samph[idx] = uh;
  *(uint2*)&sampl[idx] = ul;
}

// ---------------- F2: samp rows {m*32+cb} -(wop)-> xnew[ch][hw] -(W1',b1)-> out ----
// grid (32, 8), 512 thr. Phase-2 contracts over ch (phase-1 M) via pre-split Yh/Yl[j][ch].
__global__ __launch_bounds__(512, 2) void fused_op_out(
    const ushort* __restrict__ samph, const ushort* __restrict__ sampl,
    const ushort* __restrict__ oph, const ushort* __restrict__ opl,
    const ushort* __restrict__ W1h, const ushort* __restrict__ W1l,
    const float* __restrict__ b1, float* __restrict__ out)
{
  // region A (0..32767): phase1 Ah@0 Al@8192 Bh@16384 Bl@24576
  //                      phase2 W1h_s@0 W1l_s@8192
  // region B: Yh@32768(34816) Yl@67584(34816) -> total 102400
  __shared__ __align__(16) char smem[102400];
  __shared__ float b1_s[128];
  ushort (*Ah_s)[32]  = (ushort(*)[32])(smem);
  ushort (*Al_s)[32]  = (ushort(*)[32])(smem + 8192);
  ushort (*Bh_s)[32]  = (ushort(*)[32])(smem + 16384);
  ushort (*Bl_s)[32]  = (ushort(*)[32])(smem + 24576);
  ushort (*W1h_s)[32] = (ushort(*)[32])(smem);
  ushort (*W1l_s)[32] = (ushort(*)[32])(smem + 8192);
  ushort (*Yh)[PADU]  = (ushort(*)[PADU])(smem + 32768);
  ushort (*Yl)[PADU]  = (ushort(*)[PADU])(smem + 67584);

  const int t = threadIdx.x;
  const int cb = blockIdx.x;
  const int b = blockIdx.y;
  if (t < 128) b1_s[t] = b1[t];
  const int lane = t & 63, w = t >> 6;
  const int col = lane & 15, quad = lane >> 4;
  const f32x4 z = {0.f, 0.f, 0.f, 0.f};

  // ---- phase 1: C[ch=128][j=128]; waves: 2 m-halves x 4 n-strips ----
  const int wm1 = (w & 1) << 6, wn1 = (w >> 1) << 5;
  f32x4 acc1[4][2];
  #pragma unroll
  for (int i = 0; i < 4; ++i) { acc1[i][0] = z; acc1[i][1] = z; }

  for (int kc = 0; kc < 4; ++kc) {
    const int kB = kc << 5;
    {
      const int m = t >> 2, q8 = (t & 3) << 3;
      const size_t row = (size_t)b * HW + (size_t)m * 32 + cb;
      *(uint4*)&Ah_s[m][q8] = *(const uint4*)&samph[row * 128 + kB + q8];
      *(uint4*)&Al_s[m][q8] = *(const uint4*)&sampl[row * 128 + kB + q8];
      *(uint4*)&Bh_s[m][q8] = *(const uint4*)&oph[m * 128 + kB + q8];
      *(uint4*)&Bl_s[m][q8] = *(const uint4*)&opl[m * 128 + kB + q8];
    }
    __syncthreads();
    short8 aH[4], aL[4];
    #pragma unroll
    for (int f = 0; f < 4; ++f) {
      const int row = wm1 + (f << 4) + col;
      aH[f] = *(const short8*)&Ah_s[row][quad << 3];
      aL[f] = *(const short8*)&Al_s[row][quad << 3];
    }
    #pragma unroll
    for (int g = 0; g < 2; ++g) {
      const int n = wn1 + (g << 4) + col;
      const short8 bh = *(const short8*)&Bh_s[n][quad << 3];
      const short8 bl = *(const short8*)&Bl_s[n][quad << 3];
      #pragma unroll
      for (int f = 0; f < 4; ++f) {
        acc1[f][g] = __builtin_amdgcn_mfma_f32_16x16x32_bf16(aH[f], bh, acc1[f][g], 0, 0, 0);
        acc1[f][g] = __builtin_amdgcn_mfma_f32_16x16x32_bf16(aH[f], bl, acc1[f][g], 0, 0, 0);
        acc1[f][g] = __builtin_amdgcn_mfma_f32_16x16x32_bf16(aL[f], bh, acc1[f][g], 0, 0, 0);
      }
    }
    __syncthreads();
  }

  // scatter out2 pre-split into Yh/Yl[j][ch]
  #pragma unroll
  for (int f = 0; f < 4; ++f)
    #pragma unroll
    for (int g = 0; g < 2; ++g)
      #pragma unroll
      for (int r = 0; r < 4; ++r) {
        const int ch = wm1 + (f << 4) + (quad << 2) + r;
        const int j  = wn1 + (g << 4) + col;
        ushort hi, lo;
        split2(acc1[f][g][r], hi, lo);
        Yh[j][ch] = hi;
        Yl[j][ch] = lo;
      }

  // ---- phase 2: out[o=128][j=128]; waves: 2 m-halves x 4 n-strips ----
  const int wm2 = (w & 1) << 6, wn2 = (w >> 1) << 5;
  f32x4 acc2[4][2];
  #pragma unroll
  for (int i = 0; i < 4; ++i) { acc2[i][0] = z; acc2[i][1] = z; }

  for (int j2 = 0; j2 < 4; ++j2) {
    {
      const int o = t >> 2, q8 = (t & 3) << 3;
      *(uint4*)&W1h_s[o][q8] = *(const uint4*)&W1h[o * 128 + (j2 << 5) + q8];
      *(uint4*)&W1l_s[o][q8] = *(const uint4*)&W1l[o * 128 + (j2 << 5) + q8];
    }
    __syncthreads();
    short8 aH[4], aL[4];
    #pragma unroll
    for (int f2 = 0; f2 < 4; ++f2) {
      const int row = wm2 + (f2 << 4) + col;
      aH[f2] = *(const short8*)&W1h_s[row][quad << 3];
      aL[f2] = *(const short8*)&W1l_s[row][quad << 3];
    }
    #pragma unroll
    for (int g2 = 0; g2 < 2; ++g2) {
      const int j = wn2 + (g2 << 4) + col;
      const short8 bh = *(const short8*)&Yh[j][(j2 << 5) + (quad << 3)];
      const short8 bl = *(const short8*)&Yl[j][(j2 << 5) + (quad << 3)];
      #pragma unroll
      for (int f2 = 0; f2 < 4; ++f2) {
        acc2[f2][g2] = __builtin_amdgcn_mfma_f32_16x16x32_bf16(aH[f2], bh, acc2[f2][g2], 0, 0, 0);
        acc2[f2][g2] = __builtin_amdgcn_mfma_f32_16x16x32_bf16(aH[f2], bl, acc2[f2][g2], 0, 0, 0);
        acc2[f2][g2] = __builtin_amdgcn_mfma_f32_16x16x32_bf16(aL[f2], bh, acc2[f2][g2], 0, 0, 0);
      }
    }
    __syncthreads();
  }
  const size_t obase = (size_t)b * (size_t)(128 * HW) + ((size_t)cb << 7);
  #pragma unroll
  for (int f2 = 0; f2 < 4; ++f2)
    #pragma unroll
    for (int r = 0; r < 4; ++r) {
      const int o = wm2 + (f2 << 4) + (quad << 2) + r;
      #pragma unroll
      for (int g2 = 0; g2 < 2; ++g2) {
        const int j = wn2 + (g2 << 4) + col;
        out[obase + (size_t)o * HW + j] = acc2[f2][g2][r] + b1_s[o];
      }
    }
}

extern "C" void kernel_launch(void* const* d_in, const int* in_sizes, int n_in,
                              void* d_out, int out_size, void* d_ws, size_t ws_size,
                              hipStream_t stream)
{
  const float* x    = (const float*)d_in[0];
  const float* g1   = (const float*)d_in[1];
  const float* be1  = (const float*)d_in[2];
  const float* m1   = (const float*)d_in[3];
  const float* v1   = (const float*)d_in[4];
  const float* wpw0 = (const float*)d_in[5];
  const float* wvp  = (const float*)d_in[6];
  const float* bvp  = (const float*)d_in[7];
  const float* womW = (const float*)d_in[8];
  const float* bom  = (const float*)d_in[9];
  const float* wop  = (const float*)d_in[10];
  const float* g2   = (const float*)d_in[11];
  const float* be2  = (const float*)d_in[12];
  const float* m2   = (const float*)d_in[13];
  const float* v2   = (const float*)d_in[14];
  const float* wpw1 = (const float*)d_in[15];

  char* ws = (char*)d_ws;
  float*  value = (float*) (ws + 0);          // 16 MB (b,s,cg) f32
  float*  omb   = (float*) (ws + 16777216);   //  4 MB (b,s,32) f32
  ushort* samph = (ushort*)(ws + 20971520);   //  8 MB
  ushort* sampl = (ushort*)(ws + 29360128);   //  8 MB
  size_t o = 37748736;
  ushort* W0h = (ushort*)(ws + o); o += 32768;
  ushort* W0l = (ushort*)(ws + o); o += 32768;
  ushort* W1h = (ushort*)(ws + o); o += 32768;
  ushort* W1l = (ushort*)(ws + o); o += 32768;
  ushort* vph = (ushort*)(ws + o); o += 40960;  // 160 x 128 (value 128 rows + om 32 rows)
  ushort* vpl = (ushort*)(ws + o); o += 40960;
  ushort* oph = (ushort*)(ws + o); o += 32768;
  ushort* opl = (ushort*)(ws + o); o += 32768;
  float*  b0  = (float*)(ws + o);  o += 512;
  float*  b1  = (float*)(ws + o);
  ushort* omh = vph + 128 * 128;   // om rows live at n = 128..159 of the V matrix
  ushort* oml = vpl + 128 * 128;

  prep<<<34, 256, 0, stream>>>(g1, be1, m1, v1, wpw0, g2, be2, m2, v2, wpw1,
                               wvp, womW, wop,
                               W0h, W0l, b0, W1h, W1l, b1,
                               vph, vpl, oph, opl, omh, oml);
  fused_x_valom<<<dim3(32, 8), 512, 0, stream>>>(x, W0h, W0l, b0, vph, vpl,
                                                 bvp, bom, value, omb);
  dcn_sample<<<dim3(4096), 256, 0, stream>>>(value, omb, samph, sampl);
  fused_op_out<<<dim3(32, 8), 512, 0, stream>>>(samph, sampl, oph, opl,
                                                W1h, W1l, b1, (float*)d_out);
}